// Round 4
// baseline (264.120 us; speedup 1.0000x reference)
//
#include <hip/hip_runtime.h>
#include <stdint.h>

#define HW 16384
#define NI 64
#define NM 256
#define WORDS 256  // 16384 / 64 bits

// ws layout (~40 MB used)
#define OFF_STATE_A 0u
#define OFF_STATE_B (1u << 20)
#define OFF_PACKED  (2u << 20)
#define OFF_DIOU    0x280000u
#define OFF_CRFK    0x300000u

// ---------------- Fused setup: state init + crfk weights + mask pack -------
// 1024 blocks x 256 threads; 4 px/thread. Float ops byte-identical to R2.
__global__ __launch_bounds__(256) void setup_kernel(
    const float* __restrict__ seg, const float* __restrict__ feat,
    const float* __restrict__ x, const float* __restrict__ targets,
    unsigned char* __restrict__ state, float* __restrict__ crfk,
    unsigned long long* __restrict__ packed) {
    #pragma clang fp contract(off)
    const int g = blockIdx.x * 256 + threadIdx.x;   // [0, 262144)
    const int px0 = g * 4;
    const int b = px0 >> 14;
    const int p0 = px0 & (HW - 1);
    const int y = p0 >> 7, x0 = p0 & 127;
    const int lane = threadIdx.x & 63;

    // state byte: bit0 = s1 (ret1==0.55f), bit1 = s0, bit2 = target
    const float4 xv = *(const float4*)(x + px0);
    const float4 tv = *(const float4*)(targets + px0);
    float xs[4] = {xv.x, xv.y, xv.z, xv.w};
    float ts[4] = {tv.x, tv.y, tv.z, tv.w};
    uint32_t st = 0;
    for (int j = 0; j < 4; ++j) {
        float xt = xs[j] * ts[j];
        int b1 = (xt > 0.5f) ? 1 : 0;
        int tb = (ts[j] > 0.5f) ? 1 : 0;
        st |= (uint32_t)(b1 | ((b1 ^ 1) << 1) | (tb << 2)) << (8 * j);
    }
    *(uint32_t*)(state + px0) = st;

    // crfk[b][k][p]: exact reference op order (c+10, zero-pad OOB, seq ch sums)
    const float* f = feat + (size_t)b * 3 * HW;
    float c0[4], c1[4], c2[4];
    for (int j = 0; j < 4; ++j) {
        c0[j] = f[p0 + j] + 10.0f;
        c1[j] = f[HW + p0 + j] + 10.0f;
        c2[j] = f[2 * HW + p0 + j] + 10.0f;
    }
    for (int k = 0; k < 9; ++k) {
        int dy = k / 3 - 1, dx = k % 3 - 1;
        int yy = y + dy;
        float kw[4];
        for (int j = 0; j < 4; ++j) {
            int xx = x0 + j + dx;
            float u0 = 0.0f, u1 = 0.0f, u2 = 0.0f;
            if ((unsigned)yy < 128u && (unsigned)xx < 128u) {
                int q = yy * 128 + xx;
                u0 = f[q] + 10.0f;
                u1 = f[HW + q] + 10.0f;
                u2 = f[2 * HW + q] + 10.0f;
            }
            float d0 = u0 - c0[j], d1 = u1 - c1[j], d2 = u2 - c2[j];
            float ss = d0 * d0;
            ss = ss + d1 * d1;
            ss = ss + d2 * d2;
            float color = (-ss) / 0.5f;                       // -sum / (2*theta0^2)
            float sp = (float)(dy * dy + dx * dx) / 1800.0f;  // spatial / (2*theta1^2)
            kw[j] = 3.0f * expf(color - sp);
        }
        *(float4*)&crfk[(((size_t)b * 9 + k) << 14) + p0] =
            make_float4(kw[0], kw[1], kw[2], kw[3]);
    }

    // pack: wave gw covers 16 (mask, word) pairs
    int gw = g >> 6;  // [0, 4096), wave-uniform
    for (int t = 0; t < 16; ++t) {
        int gwi = gw * 16 + t;       // [0, 65536)
        int i = gwi >> 8, w = gwi & 255;
        float v = seg[(size_t)i * HW + w * 64 + lane];
        unsigned long long m = __ballot(v > 0.5f);
        if (lane == 0) packed[w * NM + i] = m;
    }
}

// ---------------- diou (unchanged from R2, proven) --------------------------
__global__ __launch_bounds__(256) void diou_kernel(const unsigned long long* __restrict__ packed,
                                                   const int* __restrict__ labels,
                                                   float* __restrict__ diou) {
    __shared__ unsigned long long wi[WORDS];
    int i = blockIdx.x;
    int j = threadIdx.x;
    wi[j] = packed[j * NM + i];
    __syncthreads();
    int inter = 0, si = 0, sj = 0;
    for (int w = 0; w < WORDS; ++w) {
        unsigned long long a = wi[w];
        unsigned long long b = packed[w * NM + j];
        inter += __popcll(a & b);
        si += __popcll(a);
        sj += __popcll(b);
    }
    float d = 0.0f;
    if (j > i && labels[i] == labels[j]) {
        float u = (float)(si + sj - inter);   // exact integers in f32
        d = (float)inter / u;
    }
    diou[i * NM + j] = d;
}

// ---------------- Fused compm + coef ----------------------------------------
// Each block redundantly computes all compm (max order-independent, exact),
// then its own column's min-reduce. Same float ops as R2's two kernels.
__global__ __launch_bounds__(256) void nms_tail_kernel(const float* __restrict__ diou,
                                                       const float* __restrict__ scores_in,
                                                       float* __restrict__ out) {
    #pragma clang fp contract(off)
    __shared__ float cm[NM];
    __shared__ float red[NM];
    int j = blockIdx.x, t = threadIdx.x;
    // compm[t] = exp(-2 * (max_i diou[i][t])^2)
    float m = 0.0f;
    for (int i = 0; i < NM; ++i) m = fmaxf(m, diou[i * NM + t]);
    float mm = m * m;
    cm[t] = expf(-2.0f * mm);
    __syncthreads();
    // coef_j = min_t( exp(-2*diou[t][j]^2) / compm[t] )
    float d = diou[t * NM + j];
    float dd = d * d;
    float dec = expf(-2.0f * dd);
    red[t] = dec / cm[t];
    __syncthreads();
    for (int off = 128; off > 0; off >>= 1) {
        if (t < off) red[t] = fminf(red[t], red[t + off]);
        __syncthreads();
    }
    if (t == 0) out[j] = scores_in[j] * red[0];
}

// ---------------- CRF: two iterations per launch via halo recompute ---------
// 256 blocks (64 images x 4 tiles of 32 output rows) x 1024 threads.
// iter A: rows [wlo,whi) (<=34 rows) from global sIn -> LDS (identical values
// to a full sweep: reads complete iter-t state). iter B: 32 rows from LDS.
__global__ __launch_bounds__(1024) void crf_pair_kernel(const unsigned char* __restrict__ sIn,
                                                        unsigned char* __restrict__ sOut,
                                                        const float* __restrict__ crfk) {
    #pragma clang fp contract(off)
    __shared__ uint32_t mid32[35 * 32];  // 35 rows x 128 bytes
    unsigned char* mid = (unsigned char*)mid32;
    const int tid = threadIdx.x;
    const int b = blockIdx.x >> 2, tile = blockIdx.x & 3;
    const int r0 = tile * 32;
    const int w0 = r0 - 1;                               // window start row (may be -1)
    const int wlo = (w0 < 0) ? 0 : w0;
    const int whi = (r0 + 33 > 128) ? 128 : (r0 + 33);
    const unsigned char* sb = sIn + (size_t)b * HW;
    const float* kb = crfk + ((size_t)b * 9 << 14);
    const float l45 = 0.7985076962177716f;  // -log(0.45f)
    const float l55 = 0.5978370007556204f;  // -log(0.55f)

    // ---- iteration A ----
    for (int p = wlo * 128 + tid * 4; p < whi * 128; p += 4096) {
        int yy0 = p >> 7, xc = p & 127;
        float a0[4] = {0.f, 0.f, 0.f, 0.f}, a1[4] = {0.f, 0.f, 0.f, 0.f};
        for (int k = 0; k < 9; ++k) {
            int dy = k / 3 - 1, dx = k % 3 - 1;
            int yr = yy0 + dy;
            float4 kw4 = *(const float4*)&kb[(k << 14) + p];
            float kw[4] = {kw4.x, kw4.y, kw4.z, kw4.w};
            if ((unsigned)yr < 128u) {
                int qrow = yr * 128;
                for (int j = 0; j < 4; ++j) {
                    int xx = xc + j + dx;
                    if ((unsigned)xx < 128u) {
                        unsigned char sq = sb[qrow + xx];
                        float lx1 = (sq & 1) ? l55 : l45;
                        float lx0 = (sq & 2) ? l55 : l45;
                        float t1 = lx1 * kw[j];  // mul then add (numpy order)
                        float t0 = lx0 * kw[j];
                        a1[j] = a1[j] + t1;
                        a0[j] = a0[j] + t0;
                    }
                }
            }
        }
        uint32_t scw = *(const uint32_t*)(sb + p);
        uint32_t outw = 0;
        for (int j = 0; j < 4; ++j) {
            unsigned char sc = (scw >> (8 * j)) & 0xffu;
            float tval = (sc & 4) ? 1.0f : 0.0f;
            float e1 = expf(-a1[j]);
            float e0 = expf(-a0[j]);
            float m1 = e1 * tval;
            float f1 = m1 + 1e-6f;
            float f0 = e0 + 1e-6f;
            float den = f0 + f1;
            float r1 = f1 / den;
            float r0v = f0 / den;
            int s1 = (r1 > 0.5f) ? 1 : 0;
            int s0 = (r0v > 0.5f) ? 1 : 0;
            outw |= (uint32_t)(s1 | (s0 << 1) | (sc & 4)) << (8 * j);
        }
        *(uint32_t*)&mid[p - w0 * 128] = outw;
    }
    __syncthreads();

    // ---- iteration B ----
    {
        int p = r0 * 128 + tid * 4;
        int yy0 = p >> 7, xc = p & 127;
        const unsigned char* mb = mid - w0 * 128;  // mb[q] == iter t+1 state at pixel q
        float a0[4] = {0.f, 0.f, 0.f, 0.f}, a1[4] = {0.f, 0.f, 0.f, 0.f};
        for (int k = 0; k < 9; ++k) {
            int dy = k / 3 - 1, dx = k % 3 - 1;
            int yr = yy0 + dy;
            float4 kw4 = *(const float4*)&kb[(k << 14) + p];
            float kw[4] = {kw4.x, kw4.y, kw4.z, kw4.w};
            if ((unsigned)yr < 128u) {   // taps stay within [wlo,whi) by construction
                int qrow = yr * 128;
                for (int j = 0; j < 4; ++j) {
                    int xx = xc + j + dx;
                    if ((unsigned)xx < 128u) {
                        unsigned char sq = mb[qrow + xx];
                        float lx1 = (sq & 1) ? l55 : l45;
                        float lx0 = (sq & 2) ? l55 : l45;
                        float t1 = lx1 * kw[j];
                        float t0 = lx0 * kw[j];
                        a1[j] = a1[j] + t1;
                        a0[j] = a0[j] + t0;
                    }
                }
            }
        }
        uint32_t scw = *(const uint32_t*)(mb + p);   // target bit is time-invariant
        uint32_t outw = 0;
        for (int j = 0; j < 4; ++j) {
            unsigned char sc = (scw >> (8 * j)) & 0xffu;
            float tval = (sc & 4) ? 1.0f : 0.0f;
            float e1 = expf(-a1[j]);
            float e0 = expf(-a0[j]);
            float m1 = e1 * tval;
            float f1 = m1 + 1e-6f;
            float f0 = e0 + 1e-6f;
            float den = f0 + f1;
            float r1 = f1 / den;
            float r0v = f0 / den;
            int s1 = (r1 > 0.5f) ? 1 : 0;
            int s0 = (r0v > 0.5f) ? 1 : 0;
            outw |= (uint32_t)(s1 | (s0 << 1) | (sc & 4)) << (8 * j);
        }
        *(uint32_t*)(sOut + (size_t)b * HW + p) = outw;
    }
}

// ---------------- Tail: masks + counts + valid (proven R2) ------------------
__global__ __launch_bounds__(256) void tail_kernel(const unsigned char* __restrict__ s,
                                                   float* __restrict__ outMasks,
                                                   float* __restrict__ outValid) {
    __shared__ int red[256];
    int b = blockIdx.x, t = threadIdx.x;
    int cnt = 0;
    for (int k = 0; k < 64; ++k) {
        int p = k * 256 + t;
        int v = s[(size_t)b * HW + p] & 1;
        outMasks[(size_t)b * HW + p] = (float)v;
        cnt += v;
    }
    red[t] = cnt;
    __syncthreads();
    for (int off = 128; off > 0; off >>= 1) {
        if (t < off) red[t] += red[t + off];
        __syncthreads();
    }
    // 16384*0.05 = 819.2, 16384*0.95 = 15564.8; counts are integers
    if (t == 0) outValid[b] = (red[0] >= 820 && red[0] <= 15564) ? 1.0f : 0.0f;
}

extern "C" void kernel_launch(void* const* d_in, const int* in_sizes, int n_in,
                              void* d_out, int out_size, void* d_ws, size_t ws_size,
                              hipStream_t stream) {
    const float* seg = (const float*)d_in[0];
    const float* cate_scores = (const float*)d_in[1];
    const float* feat = (const float*)d_in[2];
    const float* x = (const float*)d_in[3];
    const float* targets = (const float*)d_in[4];
    const int* labels = (const int*)d_in[5];
    float* out = (float*)d_out;
    char* ws = (char*)d_ws;

    unsigned char* stateA = (unsigned char*)(ws + OFF_STATE_A);
    unsigned char* stateB = (unsigned char*)(ws + OFF_STATE_B);
    unsigned long long* packed = (unsigned long long*)(ws + OFF_PACKED);
    float* diou = (float*)(ws + OFF_DIOU);
    float* crfk = (float*)(ws + OFF_CRFK);

    // 1. fused setup
    setup_kernel<<<1024, 256, 0, stream>>>(seg, feat, x, targets, stateA, crfk, packed);
    // 2-3. NMS
    diou_kernel<<<NM, 256, 0, stream>>>(packed, labels, diou);
    nms_tail_kernel<<<NM, 256, 0, stream>>>(diou, cate_scores, out);
    // 4-8. CRF: 5 launches x 2 iterations
    unsigned char* sIn = stateA;
    unsigned char* sOut = stateB;
    for (int pair = 0; pair < 5; ++pair) {
        crf_pair_kernel<<<NM, 1024, 0, stream>>>(sIn, sOut, crfk);
        unsigned char* tmp = sIn; sIn = sOut; sOut = tmp;
    }
    // 9. tail (sIn = final state after 10 iterations)
    tail_kernel<<<NI, 256, 0, stream>>>(sIn, out + NM, out + NM + (size_t)NI * HW);
}

// Round 5
// 222.123 us; speedup vs baseline: 1.1891x; 1.1891x over previous
//
#include <hip/hip_runtime.h>
#include <stdint.h>

#define HW 16384
#define NI 64
#define NM 256
#define WORDS 256  // 16384 / 64 bits

// ws layout (~40 MB used)
#define OFF_STATE_A 0u
#define OFF_STATE_B (1u << 20)
#define OFF_PACKED  (2u << 20)
#define OFF_DIOU    0x280000u
#define OFF_COMPM   0x2C0000u
#define OFF_CRFK    0x300000u

// ---------------- Fused setup: state init + crfk weights + mask pack -------
// 1024 blocks x 256 threads; 4 px/thread. Float ops byte-identical to R2.
__global__ __launch_bounds__(256) void setup_kernel(
    const float* __restrict__ seg, const float* __restrict__ feat,
    const float* __restrict__ x, const float* __restrict__ targets,
    unsigned char* __restrict__ state, float* __restrict__ crfk,
    unsigned long long* __restrict__ packed) {
    #pragma clang fp contract(off)
    const int g = blockIdx.x * 256 + threadIdx.x;   // [0, 262144)
    const int px0 = g * 4;
    const int b = px0 >> 14;
    const int p0 = px0 & (HW - 1);
    const int y = p0 >> 7, x0 = p0 & 127;
    const int lane = threadIdx.x & 63;

    // state byte: bit0 = s1 (ret1==0.55f), bit1 = s0, bit2 = target
    const float4 xv = *(const float4*)(x + px0);
    const float4 tv = *(const float4*)(targets + px0);
    float xs[4] = {xv.x, xv.y, xv.z, xv.w};
    float ts[4] = {tv.x, tv.y, tv.z, tv.w};
    uint32_t st = 0;
    for (int j = 0; j < 4; ++j) {
        float xt = xs[j] * ts[j];
        int b1 = (xt > 0.5f) ? 1 : 0;
        int tb = (ts[j] > 0.5f) ? 1 : 0;
        st |= (uint32_t)(b1 | ((b1 ^ 1) << 1) | (tb << 2)) << (8 * j);
    }
    *(uint32_t*)(state + px0) = st;

    // crfk[b][k][p]: exact reference op order (c+10, zero-pad OOB, seq ch sums)
    const float* f = feat + (size_t)b * 3 * HW;
    float c0[4], c1[4], c2[4];
    for (int j = 0; j < 4; ++j) {
        c0[j] = f[p0 + j] + 10.0f;
        c1[j] = f[HW + p0 + j] + 10.0f;
        c2[j] = f[2 * HW + p0 + j] + 10.0f;
    }
    for (int k = 0; k < 9; ++k) {
        int dy = k / 3 - 1, dx = k % 3 - 1;
        int yy = y + dy;
        float kw[4];
        for (int j = 0; j < 4; ++j) {
            int xx = x0 + j + dx;
            float u0 = 0.0f, u1 = 0.0f, u2 = 0.0f;
            if ((unsigned)yy < 128u && (unsigned)xx < 128u) {
                int q = yy * 128 + xx;
                u0 = f[q] + 10.0f;
                u1 = f[HW + q] + 10.0f;
                u2 = f[2 * HW + q] + 10.0f;
            }
            float d0 = u0 - c0[j], d1 = u1 - c1[j], d2 = u2 - c2[j];
            float ss = d0 * d0;
            ss = ss + d1 * d1;
            ss = ss + d2 * d2;
            float color = (-ss) / 0.5f;                       // -sum / (2*theta0^2)
            float sp = (float)(dy * dy + dx * dx) / 1800.0f;  // spatial / (2*theta1^2)
            kw[j] = 3.0f * expf(color - sp);
        }
        *(float4*)&crfk[(((size_t)b * 9 + k) << 14) + p0] =
            make_float4(kw[0], kw[1], kw[2], kw[3]);
    }

    // pack: wave gw covers 16 (mask, word) pairs
    int gw = g >> 6;  // [0, 4096), wave-uniform
    for (int t = 0; t < 16; ++t) {
        int gwi = gw * 16 + t;       // [0, 65536)
        int i = gwi >> 8, w = gwi & 255;
        float v = seg[(size_t)i * HW + w * 64 + lane];
        unsigned long long m = __ballot(v > 0.5f);
        if (lane == 0) packed[w * NM + i] = m;
    }
}

// ---------------- diou (proven) ---------------------------------------------
__global__ __launch_bounds__(256) void diou_kernel(const unsigned long long* __restrict__ packed,
                                                   const int* __restrict__ labels,
                                                   float* __restrict__ diou) {
    __shared__ unsigned long long wi[WORDS];
    int i = blockIdx.x;
    int j = threadIdx.x;
    wi[j] = packed[j * NM + i];
    __syncthreads();
    int inter = 0, si = 0, sj = 0;
    for (int w = 0; w < WORDS; ++w) {
        unsigned long long a = wi[w];
        unsigned long long b = packed[w * NM + j];
        inter += __popcll(a & b);
        si += __popcll(a);
        sj += __popcll(b);
    }
    float d = 0.0f;
    if (j > i && labels[i] == labels[j]) {
        float u = (float)(si + sj - inter);   // exact integers in f32
        d = (float)inter / u;
    }
    diou[i * NM + j] = d;
}

// compm[j] = exp(-2*(max_i diou[i][j])^2) — R2-proven tree reduce (1 load/thread).
__global__ __launch_bounds__(256) void compm_kernel(const float* __restrict__ diou,
                                                    float* __restrict__ compm) {
    #pragma clang fp contract(off)
    __shared__ float red[NM];
    int j = blockIdx.x, i = threadIdx.x;
    red[i] = diou[i * NM + j];
    __syncthreads();
    for (int off = 128; off > 0; off >>= 1) {
        if (i < off) red[i] = fmaxf(red[i], red[i + off]);
        __syncthreads();
    }
    if (i == 0) {
        float m = red[0];
        float t = m * m;
        compm[j] = expf(-2.0f * t);
    }
}

// out[j] = scores[j] * min_i( exp(-2*diou[i][j]^2) / compm[i] ) — R2-proven.
__global__ __launch_bounds__(256) void coef_kernel(const float* __restrict__ diou,
                                                   const float* __restrict__ compm,
                                                   const float* __restrict__ scores_in,
                                                   float* __restrict__ out) {
    #pragma clang fp contract(off)
    __shared__ float red[NM];
    int j = blockIdx.x, i = threadIdx.x;
    float d = diou[i * NM + j];
    float dd = d * d;
    float dec = expf(-2.0f * dd);
    red[i] = dec / compm[i];
    __syncthreads();
    for (int off = 128; off > 0; off >>= 1) {
        if (i < off) red[i] = fminf(red[i], red[i + off]);
        __syncthreads();
    }
    if (i == 0) out[j] = scores_in[j] * red[0];
}

// ---------------- CRF: two iterations per launch via halo recompute ---------
// 256 blocks (64 images x 4 tiles of 32 output rows) x 1024 threads.
__global__ __launch_bounds__(1024) void crf_pair_kernel(const unsigned char* __restrict__ sIn,
                                                        unsigned char* __restrict__ sOut,
                                                        const float* __restrict__ crfk) {
    #pragma clang fp contract(off)
    __shared__ uint32_t mid32[35 * 32];  // 35 rows x 128 bytes
    unsigned char* mid = (unsigned char*)mid32;
    const int tid = threadIdx.x;
    const int b = blockIdx.x >> 2, tile = blockIdx.x & 3;
    const int r0 = tile * 32;
    const int w0 = r0 - 1;                               // window start row (may be -1)
    const int wlo = (w0 < 0) ? 0 : w0;
    const int whi = (r0 + 33 > 128) ? 128 : (r0 + 33);
    const unsigned char* sb = sIn + (size_t)b * HW;
    const float* kb = crfk + ((size_t)b * 9 << 14);
    const float l45 = 0.7985076962177716f;  // -log(0.45f)
    const float l55 = 0.5978370007556204f;  // -log(0.55f)

    // ---- iteration A: window rows from global state ----
    for (int p = wlo * 128 + tid * 4; p < whi * 128; p += 4096) {
        int yy0 = p >> 7, xc = p & 127;
        float a0[4] = {0.f, 0.f, 0.f, 0.f}, a1[4] = {0.f, 0.f, 0.f, 0.f};
        for (int k = 0; k < 9; ++k) {
            int dy = k / 3 - 1, dx = k % 3 - 1;
            int yr = yy0 + dy;
            float4 kw4 = *(const float4*)&kb[(k << 14) + p];
            float kw[4] = {kw4.x, kw4.y, kw4.z, kw4.w};
            if ((unsigned)yr < 128u) {
                int qrow = yr * 128;
                for (int j = 0; j < 4; ++j) {
                    int xx = xc + j + dx;
                    if ((unsigned)xx < 128u) {
                        unsigned char sq = sb[qrow + xx];
                        float lx1 = (sq & 1) ? l55 : l45;
                        float lx0 = (sq & 2) ? l55 : l45;
                        float t1 = lx1 * kw[j];  // mul then add (numpy order)
                        float t0 = lx0 * kw[j];
                        a1[j] = a1[j] + t1;
                        a0[j] = a0[j] + t0;
                    }
                }
            }
        }
        uint32_t scw = *(const uint32_t*)(sb + p);
        uint32_t outw = 0;
        for (int j = 0; j < 4; ++j) {
            unsigned char sc = (scw >> (8 * j)) & 0xffu;
            float tval = (sc & 4) ? 1.0f : 0.0f;
            float e1 = expf(-a1[j]);
            float e0 = expf(-a0[j]);
            float m1 = e1 * tval;
            float f1 = m1 + 1e-6f;
            float f0 = e0 + 1e-6f;
            float den = f0 + f1;
            float r1 = f1 / den;
            float r0v = f0 / den;
            int s1 = (r1 > 0.5f) ? 1 : 0;
            int s0 = (r0v > 0.5f) ? 1 : 0;
            outw |= (uint32_t)(s1 | (s0 << 1) | (sc & 4)) << (8 * j);
        }
        *(uint32_t*)&mid[p - w0 * 128] = outw;
    }
    __syncthreads();

    // ---- iteration B: 32 output rows from LDS ----
    {
        int p = r0 * 128 + tid * 4;
        int yy0 = p >> 7, xc = p & 127;
        const unsigned char* mb = mid - w0 * 128;  // mb[q] == iter t+1 state at pixel q
        float a0[4] = {0.f, 0.f, 0.f, 0.f}, a1[4] = {0.f, 0.f, 0.f, 0.f};
        for (int k = 0; k < 9; ++k) {
            int dy = k / 3 - 1, dx = k % 3 - 1;
            int yr = yy0 + dy;
            float4 kw4 = *(const float4*)&kb[(k << 14) + p];
            float kw[4] = {kw4.x, kw4.y, kw4.z, kw4.w};
            if ((unsigned)yr < 128u) {   // taps stay within window by construction
                int qrow = yr * 128;
                for (int j = 0; j < 4; ++j) {
                    int xx = xc + j + dx;
                    if ((unsigned)xx < 128u) {
                        unsigned char sq = mb[qrow + xx];
                        float lx1 = (sq & 1) ? l55 : l45;
                        float lx0 = (sq & 2) ? l55 : l45;
                        float t1 = lx1 * kw[j];
                        float t0 = lx0 * kw[j];
                        a1[j] = a1[j] + t1;
                        a0[j] = a0[j] + t0;
                    }
                }
            }
        }
        uint32_t scw = *(const uint32_t*)(mb + p);   // target bit is time-invariant
        uint32_t outw = 0;
        for (int j = 0; j < 4; ++j) {
            unsigned char sc = (scw >> (8 * j)) & 0xffu;
            float tval = (sc & 4) ? 1.0f : 0.0f;
            float e1 = expf(-a1[j]);
            float e0 = expf(-a0[j]);
            float m1 = e1 * tval;
            float f1 = m1 + 1e-6f;
            float f0 = e0 + 1e-6f;
            float den = f0 + f1;
            float r1 = f1 / den;
            float r0v = f0 / den;
            int s1 = (r1 > 0.5f) ? 1 : 0;
            int s0 = (r0v > 0.5f) ? 1 : 0;
            outw |= (uint32_t)(s1 | (s0 << 1) | (sc & 4)) << (8 * j);
        }
        *(uint32_t*)(sOut + (size_t)b * HW + p) = outw;
    }
}

// ---------------- Tail: masks + counts + valid (proven) ---------------------
__global__ __launch_bounds__(256) void tail_kernel(const unsigned char* __restrict__ s,
                                                   float* __restrict__ outMasks,
                                                   float* __restrict__ outValid) {
    __shared__ int red[256];
    int b = blockIdx.x, t = threadIdx.x;
    int cnt = 0;
    for (int k = 0; k < 64; ++k) {
        int p = k * 256 + t;
        int v = s[(size_t)b * HW + p] & 1;
        outMasks[(size_t)b * HW + p] = (float)v;
        cnt += v;
    }
    red[t] = cnt;
    __syncthreads();
    for (int off = 128; off > 0; off >>= 1) {
        if (t < off) red[t] += red[t + off];
        __syncthreads();
    }
    // 16384*0.05 = 819.2, 16384*0.95 = 15564.8; counts are integers
    if (t == 0) outValid[b] = (red[0] >= 820 && red[0] <= 15564) ? 1.0f : 0.0f;
}

extern "C" void kernel_launch(void* const* d_in, const int* in_sizes, int n_in,
                              void* d_out, int out_size, void* d_ws, size_t ws_size,
                              hipStream_t stream) {
    const float* seg = (const float*)d_in[0];
    const float* cate_scores = (const float*)d_in[1];
    const float* feat = (const float*)d_in[2];
    const float* x = (const float*)d_in[3];
    const float* targets = (const float*)d_in[4];
    const int* labels = (const int*)d_in[5];
    float* out = (float*)d_out;
    char* ws = (char*)d_ws;

    unsigned char* stateA = (unsigned char*)(ws + OFF_STATE_A);
    unsigned char* stateB = (unsigned char*)(ws + OFF_STATE_B);
    unsigned long long* packed = (unsigned long long*)(ws + OFF_PACKED);
    float* diou = (float*)(ws + OFF_DIOU);
    float* compm = (float*)(ws + OFF_COMPM);
    float* crfk = (float*)(ws + OFF_CRFK);

    // 1. fused setup
    setup_kernel<<<1024, 256, 0, stream>>>(seg, feat, x, targets, stateA, crfk, packed);
    // 2-4. NMS
    diou_kernel<<<NM, 256, 0, stream>>>(packed, labels, diou);
    compm_kernel<<<NM, 256, 0, stream>>>(diou, compm);
    coef_kernel<<<NM, 256, 0, stream>>>(diou, compm, cate_scores, out);
    // 5-9. CRF: 5 launches x 2 iterations
    unsigned char* sIn = stateA;
    unsigned char* sOut = stateB;
    for (int pair = 0; pair < 5; ++pair) {
        crf_pair_kernel<<<NM, 1024, 0, stream>>>(sIn, sOut, crfk);
        unsigned char* tmp = sIn; sIn = sOut; sOut = tmp;
    }
    // 10. tail (sIn = final state after 10 iterations)
    tail_kernel<<<NI, 256, 0, stream>>>(sIn, out + NM, out + NM + (size_t)NI * HW);
}